// Round 1
// baseline (108.582 us; speedup 1.0000x reference)
//
#include <hip/hip_runtime.h>
#include <math.h>

// GroupNorm2dInteger: x (64,128,64,64) f32, per-sample integer-quantized groupnorm.
// Pass 1: per-sample sum / sumsq (f64, deterministic tree reduce).
// Pass 2: quantize mean/var, integer LUT isqrt -> per-sample (mu, inv_sqrt) params.
// Pass 3: elementwise (x-mu)*inv_sqrt, floor-quant Q8.4 -> float + uint8 bits.

#define NSAMP 64
#define SELEMS (128 * 64 * 64)          // 524288 per sample
#define RBLOCKS_PER 16                  // reduction blocks per sample
#define RBLOCKS (NSAMP * RBLOCKS_PER)   // 1024
#define RTHREADS 256
#define VEC_PER_RBLOCK (SELEMS / RBLOCKS_PER / 4)  // 8192 float4 per block

__global__ __launch_bounds__(RTHREADS)
void gn_reduce(const float* __restrict__ x, double* __restrict__ part) {
    int blk = blockIdx.x;
    int samp = blk >> 4;          // / RBLOCKS_PER
    int sub  = blk & 15;
    const float4* xs = reinterpret_cast<const float4*>(x)
                     + (size_t)samp * (SELEMS / 4)
                     + (size_t)sub * VEC_PER_RBLOCK;
    double s = 0.0, s2 = 0.0;
    for (int i = threadIdx.x; i < VEC_PER_RBLOCK; i += RTHREADS) {
        float4 v = xs[i];
        double a = v.x, b = v.y, c = v.z, d = v.w;
        s  += (a + b) + (c + d);
        s2 += (a * a + b * b) + (c * c + d * d);
    }
    __shared__ double sh1[RTHREADS];
    __shared__ double sh2[RTHREADS];
    int tid = threadIdx.x;
    sh1[tid] = s; sh2[tid] = s2;
    __syncthreads();
    for (int off = RTHREADS / 2; off > 0; off >>= 1) {
        if (tid < off) { sh1[tid] += sh1[tid + off]; sh2[tid] += sh2[tid + off]; }
        __syncthreads();
    }
    if (tid == 0) { part[blk * 2] = sh1[0]; part[blk * 2 + 1] = sh2[0]; }
}

__global__ void gn_finalize(const double* __restrict__ part,
                            const int* __restrict__ lut,
                            float* __restrict__ params) {
    int s = threadIdx.x;
    if (s >= NSAMP) return;
    double sum = 0.0, sum2 = 0.0;
    for (int i = 0; i < RBLOCKS_PER; ++i) {
        sum  += part[(s * RBLOCKS_PER + i) * 2];
        sum2 += part[(s * RBLOCKS_PER + i) * 2 + 1];
    }
    const double invN = 1.0 / (double)SELEMS;
    double mean = sum * invN;
    // integer_floor_quantizer(mu, 8, 4)
    double mi = floor(mean * 16.0);
    mi = fmin(fmax(mi, -128.0), 127.0);
    double mu = mi / 16.0;
    // var = mean((x-mu)^2) = E[x^2] - 2*mu*E[x] + mu^2
    double var = sum2 * invN - 2.0 * mu * mean + mu * mu;
    if (var < 0.0) var = 0.0;
    // integer_floor_quantizer(var, 16, 8) -> var_int
    double vq = floor(var * 256.0);
    vq = fmin(fmax(vq, -32768.0), 32767.0);
    int var_int = (int)vq;

    // isqrt_int (W=16, F=8, P=5), integer-exact
    int res;
    if (var_int <= 0) {
        res = 65535;
    } else {
        int msb = 31 - __clz(var_int);      // <= 14
        int x_red = var_int << (15 - msb);  // MSB at bit 15
        int idx = (x_red >> 10) & 31;       // top 5 frac bits
        int lv = lut[idx];
        int e = 24 - msb;                   // in [10, 24]
        int e2 = e >> 1;
        if (e & 1) lv = (lv * 46340) >> 15; // SQRT2_FIX = 46340
        int sh = 15 - e2;                   // in [3, 10], always >= 0
        res = lv >> sh;
        if (res < 0) res = 0;
        if (res > 65535) res = 65535;
    }
    // integer_floor_quantizer(res/256, 16, 8): floor is exact, clip at 32767
    if (res > 32767) res = 32767;

    params[s * 2]     = (float)(mi / 16.0);
    params[s * 2 + 1] = (float)res * (1.0f / 256.0f);
}

__global__ __launch_bounds__(256)
void gn_norm(const float* __restrict__ x, const float* __restrict__ params,
             float* __restrict__ outf, float* __restrict__ outu) {
    const int nvec = NSAMP * SELEMS / 4;   // 8388608
    int stride = gridDim.x * blockDim.x;
    for (int i = blockIdx.x * blockDim.x + threadIdx.x; i < nvec; i += stride) {
        int samp = i >> 17;                // / (SELEMS/4)
        float mu = params[samp * 2];
        float is = params[samp * 2 + 1];
        float4 v = reinterpret_cast<const float4*>(x)[i];
        float4 rf, ru;
        {
            float d = (v.x - mu) * is;
            float t = floorf(d * 16.0f);
            t = fminf(fmaxf(t, -128.0f), 127.0f);
            rf.x = t * 0.0625f;
            ru.x = (float)(((int)t) & 255);
        }
        {
            float d = (v.y - mu) * is;
            float t = floorf(d * 16.0f);
            t = fminf(fmaxf(t, -128.0f), 127.0f);
            rf.y = t * 0.0625f;
            ru.y = (float)(((int)t) & 255);
        }
        {
            float d = (v.z - mu) * is;
            float t = floorf(d * 16.0f);
            t = fminf(fmaxf(t, -128.0f), 127.0f);
            rf.z = t * 0.0625f;
            ru.z = (float)(((int)t) & 255);
        }
        {
            float d = (v.w - mu) * is;
            float t = floorf(d * 16.0f);
            t = fminf(fmaxf(t, -128.0f), 127.0f);
            rf.w = t * 0.0625f;
            ru.w = (float)(((int)t) & 255);
        }
        reinterpret_cast<float4*>(outf)[i] = rf;
        reinterpret_cast<float4*>(outu)[i] = ru;
    }
}

extern "C" void kernel_launch(void* const* d_in, const int* in_sizes, int n_in,
                              void* d_out, int out_size, void* d_ws, size_t ws_size,
                              hipStream_t stream) {
    const float* x  = (const float*)d_in[0];
    const int* lut  = (const int*)d_in[1];
    float* outf = (float*)d_out;
    float* outu = outf + (size_t)NSAMP * SELEMS;
    double* part  = (double*)d_ws;
    float* params = (float*)((char*)d_ws + RBLOCKS * 2 * sizeof(double));

    gn_reduce<<<RBLOCKS, RTHREADS, 0, stream>>>(x, part);
    gn_finalize<<<1, 64, 0, stream>>>(part, lut, params);
    gn_norm<<<2048, 256, 0, stream>>>(x, params, outf, outu);
}

// Round 2
// 86.006 us; speedup vs baseline: 1.2625x; 1.2625x over previous
//
#include <hip/hip_runtime.h>
#include <math.h>

// GroupNorm2dInteger: x (64,128,64,64) f32, per-sample integer-quantized groupnorm.
// Pass 1: per-sample partial sum/sumsq (f64, deterministic tree reduce), 16 blocks/sample.
// Pass 2: each norm block redundantly finalizes its sample's stats (same f64 summation
//         order -> bit-identical params), then elementwise (x-mu)*inv_sqrt with
//         floor-quant Q8.4 -> float + uint8 bits, via non-temporal stores.

#define NSAMP 64
#define SELEMS (128 * 64 * 64)          // 524288 per sample
#define RB_PER 16                       // reduction blocks per sample
#define RBLOCKS (NSAMP * RB_PER)        // 1024
#define RTHREADS 256
#define RVEC (SELEMS / RB_PER / 4)      // 8192 float4 per reduce block

#define BLK_PER_SAMP 64
#define NBLOCKS (NSAMP * BLK_PER_SAMP)  // 4096
#define NVEC_BLK (SELEMS / 4 / BLK_PER_SAMP) // 2048 float4 per norm block

typedef float f32x4 __attribute__((ext_vector_type(4)));

__global__ __launch_bounds__(RTHREADS)
void gn_reduce(const float* __restrict__ x, double* __restrict__ part) {
    int blk = blockIdx.x;
    int samp = blk >> 4;          // / RB_PER
    int sub  = blk & 15;
    const f32x4* xs = reinterpret_cast<const f32x4*>(x)
                    + (size_t)samp * (SELEMS / 4)
                    + (size_t)sub * RVEC;
    double s = 0.0, s2 = 0.0;
    for (int i = threadIdx.x; i < RVEC; i += RTHREADS) {
        f32x4 v = xs[i];
        double a = v.x, b = v.y, c = v.z, d = v.w;
        s  += (a + b) + (c + d);
        s2 += (a * a + b * b) + (c * c + d * d);
    }
    __shared__ double sh1[RTHREADS];
    __shared__ double sh2[RTHREADS];
    int tid = threadIdx.x;
    sh1[tid] = s; sh2[tid] = s2;
    __syncthreads();
    for (int off = RTHREADS / 2; off > 0; off >>= 1) {
        if (tid < off) { sh1[tid] += sh1[tid + off]; sh2[tid] += sh2[tid + off]; }
        __syncthreads();
    }
    if (tid == 0) { part[blk * 2] = sh1[0]; part[blk * 2 + 1] = sh2[0]; }
}

// Redundant per-block finalize: identical f64 summation order in every block of a
// sample -> bit-identical mu / inv_sqrt everywhere. Integer isqrt is exact.
__device__ __forceinline__ void compute_params(const double* __restrict__ part,
                                               const int* __restrict__ lut,
                                               int samp, float* mu_out, float* is_out) {
    double sum = 0.0, sum2 = 0.0;
    #pragma unroll
    for (int i = 0; i < RB_PER; ++i) {
        sum  += part[(samp * RB_PER + i) * 2];
        sum2 += part[(samp * RB_PER + i) * 2 + 1];
    }
    const double invN = 1.0 / (double)SELEMS;
    double mean = sum * invN;
    double mi = floor(mean * 16.0);                 // integer_floor_quantizer(mu,8,4)
    mi = fmin(fmax(mi, -128.0), 127.0);
    double mu = mi / 16.0;
    double var = sum2 * invN - 2.0 * mu * mean + mu * mu;
    if (var < 0.0) var = 0.0;
    double vq = floor(var * 256.0);                 // integer_floor_quantizer(var,16,8)
    vq = fmin(fmax(vq, -32768.0), 32767.0);
    int var_int = (int)vq;

    int res;
    if (var_int <= 0) {
        res = 65535;
    } else {
        int msb = 31 - __clz(var_int);      // <= 14
        int x_red = var_int << (15 - msb);  // MSB at bit 15
        int idx = (x_red >> 10) & 31;       // top 5 frac bits
        int lv = lut[idx];
        int e = 24 - msb;                   // in [10, 24]
        int e2 = e >> 1;
        if (e & 1) lv = (lv * 46340) >> 15; // SQRT2_FIX
        res = lv >> (15 - e2);              // shift in [3,10], never negative
        if (res > 65535) res = 65535;
    }
    if (res > 32767) res = 32767;           // quantize(res/256, 16, 8) clip

    *mu_out = (float)mu;
    *is_out = (float)res * (1.0f / 256.0f);
}

__global__ __launch_bounds__(256)
void gn_norm(const float* __restrict__ x, const double* __restrict__ part,
             const int* __restrict__ lut,
             float* __restrict__ outf, float* __restrict__ outu) {
    int blk  = blockIdx.x;
    int samp = blk >> 6;                    // / BLK_PER_SAMP
    int sub  = blk & 63;

    float mu, is;
    compute_params(part, lut, samp, &mu, &is);

    size_t base = (size_t)samp * (SELEMS / 4) + (size_t)sub * NVEC_BLK;
    const f32x4* xs = reinterpret_cast<const f32x4*>(x) + base;
    f32x4* of = reinterpret_cast<f32x4*>(outf) + base;
    f32x4* ou = reinterpret_cast<f32x4*>(outu) + base;

    for (int i = threadIdx.x; i < NVEC_BLK; i += 256) {
        f32x4 v = xs[i];
        f32x4 rf, ru;
        {
            float d = (v.x - mu) * is;
            float t = floorf(d * 16.0f);
            t = fminf(fmaxf(t, -128.0f), 127.0f);
            rf.x = t * 0.0625f;
            ru.x = (float)(((int)t) & 255);
        }
        {
            float d = (v.y - mu) * is;
            float t = floorf(d * 16.0f);
            t = fminf(fmaxf(t, -128.0f), 127.0f);
            rf.y = t * 0.0625f;
            ru.y = (float)(((int)t) & 255);
        }
        {
            float d = (v.z - mu) * is;
            float t = floorf(d * 16.0f);
            t = fminf(fmaxf(t, -128.0f), 127.0f);
            rf.z = t * 0.0625f;
            ru.z = (float)(((int)t) & 255);
        }
        {
            float d = (v.w - mu) * is;
            float t = floorf(d * 16.0f);
            t = fminf(fmaxf(t, -128.0f), 127.0f);
            rf.w = t * 0.0625f;
            ru.w = (float)(((int)t) & 255);
        }
        __builtin_nontemporal_store(rf, of + i);
        __builtin_nontemporal_store(ru, ou + i);
    }
}

extern "C" void kernel_launch(void* const* d_in, const int* in_sizes, int n_in,
                              void* d_out, int out_size, void* d_ws, size_t ws_size,
                              hipStream_t stream) {
    const float* x = (const float*)d_in[0];
    const int* lut = (const int*)d_in[1];
    float* outf = (float*)d_out;
    float* outu = outf + (size_t)NSAMP * SELEMS;
    double* part = (double*)d_ws;   // RBLOCKS*2 doubles = 16 KiB

    gn_reduce<<<RBLOCKS, RTHREADS, 0, stream>>>(x, part);
    gn_norm<<<NBLOCKS, 256, 0, stream>>>(x, part, lut, outf, outu);
}

// Round 3
// 83.696 us; speedup vs baseline: 1.2973x; 1.0276x over previous
//
#include <hip/hip_runtime.h>
#include <math.h>

// GroupNorm2dInteger: x (64,128,64,64) f32, per-sample integer-quantized groupnorm.
// Pass 1: per-sample partial sum/sumsq (f64, deterministic tree reduce), 16 blocks/sample.
// Pass 2: same chunk decomposition as pass 1 but traversed in REVERSE (descending 8KB
//         groups) so the freshest-in-L3 lines from pass 1 are consumed before the
//         268MB output stream evicts them. Each block redundantly finalizes its
//         sample's stats (same f64 summation order -> bit-identical params).

#define NSAMP 64
#define SELEMS (128 * 64 * 64)          // 524288 per sample
#define RB_PER 16                       // chunks per sample
#define RBLOCKS (NSAMP * RB_PER)        // 1024
#define RTHREADS 256
#define RVEC (SELEMS / RB_PER / 4)      // 8192 float4 per chunk

#define N2THREADS 512

typedef float f32x4 __attribute__((ext_vector_type(4)));

__global__ __launch_bounds__(RTHREADS)
void gn_reduce(const float* __restrict__ x, double* __restrict__ part) {
    int blk = blockIdx.x;
    int samp = blk >> 4;          // / RB_PER
    int sub  = blk & 15;
    const f32x4* xs = reinterpret_cast<const f32x4*>(x)
                    + (size_t)samp * (SELEMS / 4)
                    + (size_t)sub * RVEC;
    double s = 0.0, s2 = 0.0;
    for (int i = threadIdx.x; i < RVEC; i += RTHREADS) {
        f32x4 v = xs[i];
        double a = v.x, b = v.y, c = v.z, d = v.w;
        s  += (a + b) + (c + d);
        s2 += (a * a + b * b) + (c * c + d * d);
    }
    __shared__ double sh1[RTHREADS];
    __shared__ double sh2[RTHREADS];
    int tid = threadIdx.x;
    sh1[tid] = s; sh2[tid] = s2;
    __syncthreads();
    for (int off = RTHREADS / 2; off > 0; off >>= 1) {
        if (tid < off) { sh1[tid] += sh1[tid + off]; sh2[tid] += sh2[tid + off]; }
        __syncthreads();
    }
    if (tid == 0) { part[blk * 2] = sh1[0]; part[blk * 2 + 1] = sh2[0]; }
}

// Redundant per-block finalize: identical f64 summation order in every block of a
// sample -> bit-identical mu / inv_sqrt everywhere. Integer isqrt is exact.
__device__ __forceinline__ void compute_params(const double* __restrict__ part,
                                               const int* __restrict__ lut,
                                               int samp, float* mu_out, float* is_out) {
    double sum = 0.0, sum2 = 0.0;
    #pragma unroll
    for (int i = 0; i < RB_PER; ++i) {
        sum  += part[(samp * RB_PER + i) * 2];
        sum2 += part[(samp * RB_PER + i) * 2 + 1];
    }
    const double invN = 1.0 / (double)SELEMS;
    double mean = sum * invN;
    double mi = floor(mean * 16.0);                 // integer_floor_quantizer(mu,8,4)
    mi = fmin(fmax(mi, -128.0), 127.0);
    double mu = mi / 16.0;
    double var = sum2 * invN - 2.0 * mu * mean + mu * mu;
    if (var < 0.0) var = 0.0;
    double vq = floor(var * 256.0);                 // integer_floor_quantizer(var,16,8)
    vq = fmin(fmax(vq, -32768.0), 32767.0);
    int var_int = (int)vq;

    int res;
    if (var_int <= 0) {
        res = 65535;
    } else {
        int msb = 31 - __clz(var_int);      // <= 14
        int x_red = var_int << (15 - msb);  // MSB at bit 15
        int idx = (x_red >> 10) & 31;       // top 5 frac bits
        int lv = lut[idx];
        int e = 24 - msb;                   // in [10, 24]
        int e2 = e >> 1;
        if (e & 1) lv = (lv * 46340) >> 15; // SQRT2_FIX
        res = lv >> (15 - e2);              // shift in [3,10], never negative
        if (res > 65535) res = 65535;
    }
    if (res > 32767) res = 32767;           // quantize(res/256, 16, 8) clip

    *mu_out = (float)mu;
    *is_out = (float)res * (1.0f / 256.0f);
}

__global__ __launch_bounds__(N2THREADS)
void gn_norm(const float* __restrict__ x, const double* __restrict__ part,
             const int* __restrict__ lut,
             float* __restrict__ outf, float* __restrict__ outu) {
    int blk  = blockIdx.x;        // 0..1023, same chunk map as gn_reduce
    int samp = blk >> 4;
    int sub  = blk & 15;

    float mu, is;
    compute_params(part, lut, samp, &mu, &is);

    size_t base = (size_t)samp * (SELEMS / 4) + (size_t)sub * RVEC;
    const f32x4* xs = reinterpret_cast<const f32x4*>(x) + base;
    f32x4* of = reinterpret_cast<f32x4*>(outf) + base;
    f32x4* ou = reinterpret_cast<f32x4*>(outu) + base;

    // Reverse traversal: descending 8KB groups (freshest L3 lines first),
    // forward/coalesced within each group.
    for (int i = RVEC - N2THREADS + (int)threadIdx.x; i >= 0; i -= N2THREADS) {
        f32x4 v = xs[i];
        f32x4 rf, ru;
        {
            float d = (v.x - mu) * is;
            float t = floorf(d * 16.0f);
            t = fminf(fmaxf(t, -128.0f), 127.0f);
            rf.x = t * 0.0625f;
            ru.x = (float)(((int)t) & 255);
        }
        {
            float d = (v.y - mu) * is;
            float t = floorf(d * 16.0f);
            t = fminf(fmaxf(t, -128.0f), 127.0f);
            rf.y = t * 0.0625f;
            ru.y = (float)(((int)t) & 255);
        }
        {
            float d = (v.z - mu) * is;
            float t = floorf(d * 16.0f);
            t = fminf(fmaxf(t, -128.0f), 127.0f);
            rf.z = t * 0.0625f;
            ru.z = (float)(((int)t) & 255);
        }
        {
            float d = (v.w - mu) * is;
            float t = floorf(d * 16.0f);
            t = fminf(fmaxf(t, -128.0f), 127.0f);
            rf.w = t * 0.0625f;
            ru.w = (float)(((int)t) & 255);
        }
        __builtin_nontemporal_store(rf, of + i);
        __builtin_nontemporal_store(ru, ou + i);
    }
}

extern "C" void kernel_launch(void* const* d_in, const int* in_sizes, int n_in,
                              void* d_out, int out_size, void* d_ws, size_t ws_size,
                              hipStream_t stream) {
    const float* x = (const float*)d_in[0];
    const int* lut = (const int*)d_in[1];
    float* outf = (float*)d_out;
    float* outu = outf + (size_t)NSAMP * SELEMS;
    double* part = (double*)d_ws;   // RBLOCKS*2 doubles = 16 KiB

    gn_reduce<<<RBLOCKS, RTHREADS, 0, stream>>>(x, part);
    gn_norm<<<RBLOCKS, N2THREADS, 0, stream>>>(x, part, lut, outf, outu);
}